// Round 1
// baseline (3716.311 us; speedup 1.0000x reference)
//
#include <hip/hip_runtime.h>
#include <math.h>

// Problem constants (N,H,C,D) = (4096,16,64,1024)
#define TAU_F 0.6f

// ===================== generic fp32 tiled GEMM =====================
// C[M,N] = A[M,K] @ B[K,N] + bias[N], all row-major. BM=BN=64, BK=16.
// 256 threads, 4x4 microtile per thread. M,N multiples of 64; K multiple of 16.
__global__ __launch_bounds__(256) void gemm_bias_kernel(
    const float* __restrict__ A, int lda,
    const float* __restrict__ B, int ldb,
    const float* __restrict__ bias,
    float* __restrict__ C, int ldc, int K)
{
    __shared__ float As[16][65];
    __shared__ float Bs[16][64];
    const int tid = threadIdx.x;
    const int tx = tid & 15, ty = tid >> 4;
    const int bm = blockIdx.y * 64;
    const int bn = blockIdx.x * 64;
    const int r0 = ty * 4, c0 = tx * 4;
    const int ak = tid & 15, ar = tid >> 4;   // A loader: k fast, row slow
    const int bc = tid & 63, bk = tid >> 6;   // B loader: col fast, k slow
    float acc[4][4] = {};
    for (int k0 = 0; k0 < K; k0 += 16) {
        #pragma unroll
        for (int i = 0; i < 4; i++)
            As[ak][ar + i * 16] = A[(size_t)(bm + ar + i * 16) * lda + k0 + ak];
        #pragma unroll
        for (int i = 0; i < 4; i++)
            Bs[bk + i * 4][bc] = B[(size_t)(k0 + bk + i * 4) * ldb + bn + bc];
        __syncthreads();
        #pragma unroll
        for (int kk = 0; kk < 16; kk++) {
            float a[4], b[4];
            #pragma unroll
            for (int i = 0; i < 4; i++) a[i] = As[kk][r0 + i];
            #pragma unroll
            for (int j = 0; j < 4; j++) b[j] = Bs[kk][c0 + j];
            #pragma unroll
            for (int i = 0; i < 4; i++)
                #pragma unroll
                for (int j = 0; j < 4; j++)
                    acc[i][j] += a[i] * b[j];
        }
        __syncthreads();
    }
    #pragma unroll
    for (int i = 0; i < 4; i++)
        #pragma unroll
        for (int j = 0; j < 4; j++)
            C[(size_t)(bm + r0 + i) * ldc + bn + c0 + j] =
                acc[i][j] + bias[bn + c0 + j];
}

// ===================== _mh_rms: x <- l2norm_per(n,h)(x) * gamma * 8 =====================
// One wave per (n,h) row-head (64 elements). grid = 65536/4 blocks of 256.
__global__ __launch_bounds__(256) void mh_rms_kernel(
    float* __restrict__ data, int ld, const float* __restrict__ gamma)
{
    const int w = blockIdx.x * 4 + (threadIdx.x >> 6);
    const int lane = threadIdx.x & 63;
    const int n = w >> 4, h = w & 15;
    float* p = data + (size_t)n * ld + h * 64 + lane;
    float x = *p;
    float ss = x * x;
    #pragma unroll
    for (int off = 32; off; off >>= 1) ss += __shfl_xor(ss, off, 64);
    float nrm = sqrtf(ss);
    float s = 8.0f * gamma[h * 64 + lane] / fmaxf(nrm, 1e-12f);
    *p = x * s;
}

// ===================== per-row inverse L2 norm over D=1024 =====================
__global__ __launch_bounds__(256) void rowinv_kernel(
    const float* __restrict__ base, int ld, float* __restrict__ out)
{
    const int n = blockIdx.x;
    const float4* row = (const float4*)(base + (size_t)n * ld);
    float4 v = row[threadIdx.x];
    float ss = v.x * v.x + v.y * v.y + v.z * v.z + v.w * v.w;
    #pragma unroll
    for (int off = 32; off; off >>= 1) ss += __shfl_xor(ss, off, 64);
    __shared__ float wsum[4];
    if ((threadIdx.x & 63) == 0) wsum[threadIdx.x >> 6] = ss;
    __syncthreads();
    if (threadIdx.x == 0)
        out[n] = 1.0f / fmaxf(sqrtf(wsum[0] + wsum[1] + wsum[2] + wsum[3]), 1e-12f);
}

// ===================== cosine-sim GEMM with fused row max/argmax =====================
// sim[n,m] = (A[n,:] . Bm[m,:]) * ainv[n] * binv[m]. Only per-row top-1 kept.
// grid.x = 64 n-blocks (64 rows each), grid.y = 8 m-chunks (512 m each).
__global__ __launch_bounds__(256) void simmax_kernel(
    const float* __restrict__ A, int lda,
    const float* __restrict__ Bm,
    const float* __restrict__ ainv, const float* __restrict__ binv,
    float* __restrict__ pval, int* __restrict__ pidx)
{
    __shared__ float As[16][65];
    __shared__ float Bs[16][65];
    const int tid = threadIdx.x;
    const int tx = tid & 15, ty = tid >> 4;
    const int bn = blockIdx.x * 64;
    const int chunk = blockIdx.y;
    const int r0 = ty * 4, c0 = tx * 4;
    const int ak = tid & 15, ar = tid >> 4;
    float bv[4] = {-1e30f, -1e30f, -1e30f, -1e30f};
    int bi[4] = {0, 0, 0, 0};
    float ai[4];
    #pragma unroll
    for (int i = 0; i < 4; i++) ai[i] = ainv[bn + r0 + i];

    for (int t = 0; t < 8; t++) {
        const int m0 = chunk * 512 + t * 64;
        float acc[4][4] = {};
        for (int k0 = 0; k0 < 1024; k0 += 16) {
            #pragma unroll
            for (int i = 0; i < 4; i++)
                As[ak][ar + i * 16] = A[(size_t)(bn + ar + i * 16) * lda + k0 + ak];
            #pragma unroll
            for (int i = 0; i < 4; i++)
                Bs[ak][ar + i * 16] = Bm[(size_t)(m0 + ar + i * 16) * 1024 + k0 + ak];
            __syncthreads();
            #pragma unroll
            for (int kk = 0; kk < 16; kk++) {
                float a[4], b[4];
                #pragma unroll
                for (int i = 0; i < 4; i++) a[i] = As[kk][r0 + i];
                #pragma unroll
                for (int j = 0; j < 4; j++) b[j] = Bs[kk][c0 + j];
                #pragma unroll
                for (int i = 0; i < 4; i++)
                    #pragma unroll
                    for (int j = 0; j < 4; j++)
                        acc[i][j] += a[i] * b[j];
            }
            __syncthreads();
        }
        #pragma unroll
        for (int i = 0; i < 4; i++)
            #pragma unroll
            for (int j = 0; j < 4; j++) {
                int m = m0 + c0 + j;
                float s = acc[i][j] * ai[i] * binv[m];
                if (s > bv[i]) { bv[i] = s; bi[i] = m; }
            }
    }
    // block reduce across the 16 tx threads sharing each row group
    __shared__ float rv[64][17];
    __shared__ int ri[64][17];
    #pragma unroll
    for (int i = 0; i < 4; i++) { rv[r0 + i][tx] = bv[i]; ri[r0 + i][tx] = bi[i]; }
    __syncthreads();
    if (tid < 64) {
        float best = -1e30f; int besti = 0x7fffffff;
        for (int x = 0; x < 16; x++) {
            float v = rv[tid][x]; int ix = ri[tid][x];
            if (v > best || (v == best && ix < besti)) { best = v; besti = ix; }
        }
        pval[chunk * 4096 + bn + tid] = best;
        pidx[chunk * 4096 + bn + tid] = besti;
    }
}

__global__ void simreduce_kernel(const float* __restrict__ pval,
                                 const int* __restrict__ pidx,
                                 float* __restrict__ bv, int* __restrict__ bi)
{
    const int n = blockIdx.x * 256 + threadIdx.x;
    float best = -1e30f; int besti = 0x7fffffff;
    for (int c = 0; c < 8; c++) {
        float v = pval[c * 4096 + n]; int ix = pidx[c * 4096 + n];
        if (v > best || (v == best && ix < besti)) { best = v; besti = ix; }
    }
    bv[n] = best; bi[n] = besti;
}

__global__ void zero2_kernel(float* p) { if (threadIdx.x < 2) p[threadIdx.x] = 0.f; }

// ===================== combine + sumsq(v_flat), sumsq(combined_v) =====================
__global__ __launch_bounds__(256) void combine_kernel(
    const float* __restrict__ QKV,
    const float* __restrict__ k0, const float* __restrict__ v0,
    const float* __restrict__ k1, const float* __restrict__ v1,
    const float* __restrict__ bv0, const int* __restrict__ bi0,
    const float* __restrict__ bv1, const int* __restrict__ bi1,
    float* __restrict__ CK, float* __restrict__ CV, float* __restrict__ ss)
{
    const int n = blockIdx.x;
    const int t = threadIdx.x;
    const bool va0 = bv0[n] > TAU_F; const int i0 = bi0[n];
    const bool va1 = bv1[n] > TAU_F; const int i1 = bi1[n];
    float4 kf = ((const float4*)(QKV + (size_t)n * 3072 + 1024))[t];
    float4 vf = ((const float4*)(QKV + (size_t)n * 3072 + 2048))[t];
    float4 kg0 = va0 ? ((const float4*)(k0 + (size_t)i0 * 1024))[t] : kf;
    float4 vg0 = va0 ? ((const float4*)(v0 + (size_t)i0 * 1024))[t] : vf;
    float4 kg1 = va1 ? ((const float4*)(k1 + (size_t)i1 * 1024))[t] : kf;
    float4 vg1 = va1 ? ((const float4*)(v1 + (size_t)i1 * 1024))[t] : vf;
    float4 ck, cv;
    ck.x = 0.5f * kg0.x + 0.5f * kg1.x + kf.x;
    ck.y = 0.5f * kg0.y + 0.5f * kg1.y + kf.y;
    ck.z = 0.5f * kg0.z + 0.5f * kg1.z + kf.z;
    ck.w = 0.5f * kg0.w + 0.5f * kg1.w + kf.w;
    cv.x = 0.5f * vg0.x + 0.5f * vg1.x + vf.x;
    cv.y = 0.5f * vg0.y + 0.5f * vg1.y + vf.y;
    cv.z = 0.5f * vg0.z + 0.5f * vg1.z + vf.z;
    cv.w = 0.5f * vg0.w + 0.5f * vg1.w + vf.w;
    ((float4*)(CK + (size_t)n * 1024))[t] = ck;
    ((float4*)(CV + (size_t)n * 1024))[t] = cv;
    float s0 = vf.x * vf.x + vf.y * vf.y + vf.z * vf.z + vf.w * vf.w;
    float s1 = cv.x * cv.x + cv.y * cv.y + cv.z * cv.z + cv.w * cv.w;
    #pragma unroll
    for (int off = 32; off; off >>= 1) {
        s0 += __shfl_xor(s0, off, 64);
        s1 += __shfl_xor(s1, off, 64);
    }
    __shared__ float w0[4], w1[4];
    if ((t & 63) == 0) { w0[t >> 6] = s0; w1[t >> 6] = s1; }
    __syncthreads();
    if (t == 0) {
        atomicAdd(ss + 0, w0[0] + w0[1] + w0[2] + w0[3]);
        atomicAdd(ss + 1, w1[0] + w1[1] + w1[2] + w1[3]);
    }
}

// CV *= sv, sv = sqrt(ss[0]/ss[1])   (note: sk cancels inside _mh_rms, never needed)
__global__ __launch_bounds__(256) void vscale_kernel(float* __restrict__ CV,
                                                     const float* __restrict__ ss)
{
    const float sv = sqrtf(ss[0] / ss[1]);
    const int i = blockIdx.x * 256 + threadIdx.x;
    float4 v = ((float4*)CV)[i];
    v.x *= sv; v.y *= sv; v.z *= sv; v.w *= sv;
    ((float4*)CV)[i] = v;
}

// ===================== flash attention per head =====================
// grid = (64 q-tiles, 16 heads). Q from QKV (ld 3072), K/V from CK/CV (ld 1024).
__global__ __launch_bounds__(256) void attn_kernel(
    const float* __restrict__ Q,
    const float* __restrict__ Kr, const float* __restrict__ Vr,
    float* __restrict__ Ho)
{
    __shared__ float Qs[64][65];
    __shared__ float KVs[64][65];
    __shared__ float Ss[64][65];
    __shared__ float mrow[64], lrow[64], arow[64];
    const int h = blockIdx.y;
    const int n0 = blockIdx.x * 64;
    const int tid = threadIdx.x;
    const int tx = tid & 15, ty = tid >> 4;
    const int r0 = ty * 4, c0 = tx * 4;
    const int lc = tid & 63, lr = tid >> 6;

    #pragma unroll
    for (int i = 0; i < 16; i++)
        Qs[lr + i * 4][lc] = Q[(size_t)(n0 + lr + i * 4) * 3072 + h * 64 + lc];
    if (tid < 64) { mrow[tid] = -1e30f; lrow[tid] = 0.f; }
    float acc[4][4] = {};
    __syncthreads();

    for (int mt = 0; mt < 64; mt++) {
        const int m0 = mt * 64;
        #pragma unroll
        for (int i = 0; i < 16; i++)
            KVs[lr + i * 4][lc] = Kr[(size_t)(m0 + lr + i * 4) * 1024 + h * 64 + lc];
        __syncthreads();
        float s[4][4] = {};
        #pragma unroll 8
        for (int d = 0; d < 64; d++) {
            float a[4], b[4];
            #pragma unroll
            for (int i = 0; i < 4; i++) a[i] = Qs[r0 + i][d];
            #pragma unroll
            for (int j = 0; j < 4; j++) b[j] = KVs[c0 + j][d];
            #pragma unroll
            for (int i = 0; i < 4; i++)
                #pragma unroll
                for (int j = 0; j < 4; j++)
                    s[i][j] += a[i] * b[j];
        }
        #pragma unroll
        for (int i = 0; i < 4; i++)
            #pragma unroll
            for (int j = 0; j < 4; j++)
                Ss[r0 + i][c0 + j] = s[i][j] * 0.125f;
        __syncthreads();
        // V load (into KVs) overlapped with row softmax (on Ss) — independent buffers
        #pragma unroll
        for (int i = 0; i < 16; i++)
            KVs[lr + i * 4][lc] = Vr[(size_t)(m0 + lr + i * 4) * 1024 + h * 64 + lc];
        if (tid < 64) {
            const int r = tid;
            float mo = mrow[r], mn = mo;
            for (int c = 0; c < 64; c++) mn = fmaxf(mn, Ss[r][c]);
            float al = __expf(mo - mn);
            float l = lrow[r] * al;
            for (int c = 0; c < 64; c++) {
                float p = __expf(Ss[r][c] - mn);
                Ss[r][c] = p;
                l += p;
            }
            mrow[r] = mn; lrow[r] = l; arow[r] = al;
        }
        __syncthreads();
        float al[4];
        #pragma unroll
        for (int i = 0; i < 4; i++) al[i] = arow[r0 + i];
        #pragma unroll
        for (int i = 0; i < 4; i++)
            #pragma unroll
            for (int j = 0; j < 4; j++)
                acc[i][j] *= al[i];
        #pragma unroll 8
        for (int d = 0; d < 64; d++) {
            float p[4], b[4];
            #pragma unroll
            for (int i = 0; i < 4; i++) p[i] = Ss[r0 + i][d];
            #pragma unroll
            for (int j = 0; j < 4; j++) b[j] = KVs[d][c0 + j];
            #pragma unroll
            for (int i = 0; i < 4; i++)
                #pragma unroll
                for (int j = 0; j < 4; j++)
                    acc[i][j] += p[i] * b[j];
        }
        __syncthreads();
    }
    float inv[4];
    #pragma unroll
    for (int i = 0; i < 4; i++) inv[i] = 1.0f / lrow[r0 + i];
    #pragma unroll
    for (int i = 0; i < 4; i++)
        #pragma unroll
        for (int j = 0; j < 4; j++)
            Ho[(size_t)(n0 + r0 + i) * 1024 + h * 64 + c0 + j] = acc[i][j] * inv[i];
}

// ===================== launcher =====================
extern "C" void kernel_launch(void* const* d_in, const int* in_sizes, int n_in,
                              void* d_out, int out_size, void* d_ws, size_t ws_size,
                              hipStream_t stream)
{
    const float* x       = (const float*)d_in[0];
    const float* k0      = (const float*)d_in[1];
    const float* v0      = (const float*)d_in[2];
    const float* k1      = (const float*)d_in[3];
    const float* v1      = (const float*)d_in[4];
    const float* W_qkv   = (const float*)d_in[5];
    const float* b_qkv   = (const float*)d_in[6];
    const float* gamma_q = (const float*)d_in[7];
    const float* gamma_k = (const float*)d_in[8];
    const float* W_out   = (const float*)d_in[9];
    const float* b_out   = (const float*)d_in[10];
    float* out = (float*)d_out;

    // workspace layout (floats); total ~101.3 MB
    float* ws    = (float*)d_ws;
    float* QKV   = ws;                       // 4096*3072
    float* CK    = QKV + (size_t)4096 * 3072; // 4096*1024
    float* CV    = CK + (size_t)4096 * 1024;
    float* Ho    = CV + (size_t)4096 * 1024;
    float* kinv  = Ho + (size_t)4096 * 1024; // 4096
    float* k0inv = kinv + 4096;
    float* k1inv = k0inv + 4096;
    float* pval0 = k1inv + 4096;             // 8*4096
    int*   pidx0 = (int*)(pval0 + 8 * 4096);
    float* pval1 = (float*)(pidx0 + 8 * 4096);
    int*   pidx1 = (int*)(pval1 + 8 * 4096);
    float* bv0   = (float*)(pidx1 + 8 * 4096);
    int*   bi0   = (int*)(bv0 + 4096);
    float* bv1   = (float*)(bi0 + 4096);
    int*   bi1   = (int*)(bv1 + 4096);
    float* ssum  = (float*)(bi1 + 4096);     // 2 floats

    // 1. QKV = x @ W_qkv + b_qkv
    gemm_bias_kernel<<<dim3(48, 64), 256, 0, stream>>>(x, 1024, W_qkv, 3072, b_qkv,
                                                       QKV, 3072, 1024);
    // 2. q <- mh_rms(q, gamma_q) in place
    mh_rms_kernel<<<16384, 256, 0, stream>>>(QKV, 3072, gamma_q);
    // 3. inverse row norms
    rowinv_kernel<<<4096, 256, 0, stream>>>(QKV + 1024, 3072, kinv);
    rowinv_kernel<<<4096, 256, 0, stream>>>(k0, 1024, k0inv);
    rowinv_kernel<<<4096, 256, 0, stream>>>(k1, 1024, k1inv);
    // 4. fused sim + top-1
    simmax_kernel<<<dim3(64, 8), 256, 0, stream>>>(QKV + 1024, 3072, k0, kinv, k0inv,
                                                   pval0, pidx0);
    simmax_kernel<<<dim3(64, 8), 256, 0, stream>>>(QKV + 1024, 3072, k1, kinv, k1inv,
                                                   pval1, pidx1);
    simreduce_kernel<<<16, 256, 0, stream>>>(pval0, pidx0, bv0, bi0);
    simreduce_kernel<<<16, 256, 0, stream>>>(pval1, pidx1, bv1, bi1);
    // 5. combine (+ v sumsqs); sk cancels analytically, only sv needed
    zero2_kernel<<<1, 64, 0, stream>>>(ssum);
    combine_kernel<<<4096, 256, 0, stream>>>(QKV, k0, v0, k1, v1, bv0, bi0, bv1, bi1,
                                             CK, CV, ssum);
    // 6. K <- mh_rms(combined_k, gamma_k); V <- combined_v * sv
    mh_rms_kernel<<<16384, 256, 0, stream>>>(CK, 1024, gamma_k);
    vscale_kernel<<<4096, 256, 0, stream>>>(CV, ssum);
    // 7. flash attention per head
    attn_kernel<<<dim3(64, 16), 256, 0, stream>>>(QKV, CK, CV, Ho);
    // 8. out = Ho @ W_out + b_out
    gemm_bias_kernel<<<dim3(16, 64), 256, 0, stream>>>(Ho, 1024, W_out, 1024, b_out,
                                                       out, 1024, 1024);
}

// Round 2
// 896.779 us; speedup vs baseline: 4.1441x; 4.1441x over previous
//
#include <hip/hip_runtime.h>
#include <math.h>

#define TAU_F 0.6f

typedef short short8 __attribute__((ext_vector_type(8)));
typedef float floatx4 __attribute__((ext_vector_type(4)));

__device__ __forceinline__ ushort f2bf(float f) {
    unsigned u = __float_as_uint(f);
    u += 0x7FFF + ((u >> 16) & 1);
    return (ushort)(u >> 16);
}
__device__ __forceinline__ float bf2f(ushort h) {
    return __uint_as_float(((unsigned)h) << 16);
}
__device__ __forceinline__ int swz(int row, int j, int mask) { return j ^ (row & mask); }

// Stage a tile of (ROWS x CPR*16B rows) from global into LDS with XOR-chunk swizzle.
// SC = number of 1KB superchunks (= bytes/1024). Each wave handles SC/4 (or remainder).
template<int CPR, int SC>
__device__ __forceinline__ void stage_swz(ushort* lds, const char* g, int rowstride_bytes,
                                          int w, int lane)
{
    #pragma unroll
    for (int p = 0; p < (SC + 3) / 4; ++p) {
        int sc = w + p * 4;
        if (SC % 4 != 0 && sc >= SC) break;
        int LC = sc * 64 + lane;          // 16B lane-chunk index
        int r = LC / CPR;
        int s = LC % CPR;
        int j = s ^ (r & (CPR - 1));
        const char* gp = g + (size_t)r * rowstride_bytes + j * 16;
        __builtin_amdgcn_global_load_lds(
            (const __attribute__((address_space(1))) void*)gp,
            (__attribute__((address_space(3))) void*)((char*)lds + sc * 1024), 16, 0, 0);
    }
}

// ===================== MFMA NT GEMM: C[M,N] = A[M,K] * Bt[N,K]^T + bias =====================
// 128x128 tile, BK=32, 256 threads (4 waves in 2x2), 16x16x32 bf16 MFMA.
template<bool SPLIT>
__global__ __launch_bounds__(256) void gemm_nt_kernel(
    const ushort* __restrict__ Ah, const ushort* __restrict__ Al, int lda,
    const ushort* __restrict__ Bh, const ushort* __restrict__ Bl, int ldb,
    const float* __restrict__ bias, float* __restrict__ C, int ldc, int K)
{
    __shared__ __align__(16) ushort As_h[128 * 32];
    __shared__ __align__(16) ushort Bs_h[128 * 32];
    __shared__ __align__(16) ushort As_l[128 * 32];
    __shared__ __align__(16) ushort Bs_l[128 * 32];
    const int tid = threadIdx.x;
    const int w = tid >> 6, lane = tid & 63;
    const int quad = lane >> 4, c15 = lane & 15;
    const int wm = w >> 1, wn = w & 1;
    const int bm = blockIdx.y * 128, bn = blockIdx.x * 128;

    floatx4 acc[4][4];
    #pragma unroll
    for (int i = 0; i < 4; i++)
        #pragma unroll
        for (int j = 0; j < 4; j++) acc[i][j] = (floatx4){0.f, 0.f, 0.f, 0.f};

    const char* Ab = (const char*)(Ah + (size_t)bm * lda);
    const char* Bb = (const char*)(Bh + (size_t)bn * ldb);
    const char* Alb = SPLIT ? (const char*)(Al + (size_t)bm * lda) : nullptr;
    const char* Blb = SPLIT ? (const char*)(Bl + (size_t)bn * ldb) : nullptr;

    for (int k0 = 0; k0 < K; k0 += 32) {
        stage_swz<4, 8>(As_h, Ab + k0 * 2, lda * 2, w, lane);
        stage_swz<4, 8>(Bs_h, Bb + k0 * 2, ldb * 2, w, lane);
        if constexpr (SPLIT) {
            stage_swz<4, 8>(As_l, Alb + k0 * 2, lda * 2, w, lane);
            stage_swz<4, 8>(Bs_l, Blb + k0 * 2, ldb * 2, w, lane);
        }
        __syncthreads();
        short8 a_h[4], b_h[4], a_l[4], b_l[4];
        #pragma unroll
        for (int mt = 0; mt < 4; mt++) {
            int row = wm * 64 + mt * 16 + c15;
            a_h[mt] = *(const short8*)&As_h[row * 32 + swz(row, quad, 3) * 8];
            if constexpr (SPLIT)
                a_l[mt] = *(const short8*)&As_l[row * 32 + swz(row, quad, 3) * 8];
        }
        #pragma unroll
        for (int nt = 0; nt < 4; nt++) {
            int row = wn * 64 + nt * 16 + c15;
            b_h[nt] = *(const short8*)&Bs_h[row * 32 + swz(row, quad, 3) * 8];
            if constexpr (SPLIT)
                b_l[nt] = *(const short8*)&Bs_l[row * 32 + swz(row, quad, 3) * 8];
        }
        #pragma unroll
        for (int mt = 0; mt < 4; mt++)
            #pragma unroll
            for (int nt = 0; nt < 4; nt++)
                acc[mt][nt] = __builtin_amdgcn_mfma_f32_16x16x32_bf16(a_h[mt], b_h[nt], acc[mt][nt], 0, 0, 0);
        if constexpr (SPLIT) {
            #pragma unroll
            for (int mt = 0; mt < 4; mt++)
                #pragma unroll
                for (int nt = 0; nt < 4; nt++)
                    acc[mt][nt] = __builtin_amdgcn_mfma_f32_16x16x32_bf16(a_h[mt], b_l[nt], acc[mt][nt], 0, 0, 0);
            #pragma unroll
            for (int mt = 0; mt < 4; mt++)
                #pragma unroll
                for (int nt = 0; nt < 4; nt++)
                    acc[mt][nt] = __builtin_amdgcn_mfma_f32_16x16x32_bf16(a_l[mt], b_h[nt], acc[mt][nt], 0, 0, 0);
        }
        __syncthreads();
    }
    #pragma unroll
    for (int mt = 0; mt < 4; mt++)
        #pragma unroll
        for (int nt = 0; nt < 4; nt++) {
            int col = bn + wn * 64 + nt * 16 + c15;
            float bs = bias ? bias[col] : 0.f;
            #pragma unroll
            for (int r = 0; r < 4; r++) {
                int row = bm + wm * 64 + mt * 16 + quad * 4 + r;
                C[(size_t)row * ldc + col] = acc[mt][nt][r] + bs;
            }
        }
}

// ===================== sim GEMM (plain bf16) with fused per-row max/argmax =====================
__global__ __launch_bounds__(256) void simmax_mfma(
    const ushort* __restrict__ A, const ushort* __restrict__ B,
    float* __restrict__ pval, int* __restrict__ pidx)
{
    __shared__ __align__(16) ushort As_h[128 * 32];
    __shared__ __align__(16) ushort Bs_h[128 * 32];
    __shared__ float redv[128][2];
    __shared__ int   redi[128][2];
    const int tid = threadIdx.x;
    const int w = tid >> 6, lane = tid & 63;
    const int quad = lane >> 4, c15 = lane & 15;
    const int wm = w >> 1, wn = w & 1;
    const int bm = blockIdx.y * 128, bn = blockIdx.x * 128;

    floatx4 acc[4][4];
    #pragma unroll
    for (int i = 0; i < 4; i++)
        #pragma unroll
        for (int j = 0; j < 4; j++) acc[i][j] = (floatx4){0.f, 0.f, 0.f, 0.f};

    const char* Ab = (const char*)(A + (size_t)bm * 1024);
    const char* Bb = (const char*)(B + (size_t)bn * 1024);

    for (int k0 = 0; k0 < 1024; k0 += 32) {
        stage_swz<4, 8>(As_h, Ab + k0 * 2, 2048, w, lane);
        stage_swz<4, 8>(Bs_h, Bb + k0 * 2, 2048, w, lane);
        __syncthreads();
        short8 a_h[4], b_h[4];
        #pragma unroll
        for (int mt = 0; mt < 4; mt++) {
            int row = wm * 64 + mt * 16 + c15;
            a_h[mt] = *(const short8*)&As_h[row * 32 + swz(row, quad, 3) * 8];
        }
        #pragma unroll
        for (int nt = 0; nt < 4; nt++) {
            int row = wn * 64 + nt * 16 + c15;
            b_h[nt] = *(const short8*)&Bs_h[row * 32 + swz(row, quad, 3) * 8];
        }
        #pragma unroll
        for (int mt = 0; mt < 4; mt++)
            #pragma unroll
            for (int nt = 0; nt < 4; nt++)
                acc[mt][nt] = __builtin_amdgcn_mfma_f32_16x16x32_bf16(a_h[mt], b_h[nt], acc[mt][nt], 0, 0, 0);
        __syncthreads();
    }
    // per-row max/argmax (each row fully within one wave's 4 n-tiles per wn half)
    #pragma unroll
    for (int mt = 0; mt < 4; mt++)
        #pragma unroll
        for (int r = 0; r < 4; r++) {
            float bv = -1e30f; int bi = 0;
            #pragma unroll
            for (int nt = 0; nt < 4; nt++) {
                float v = acc[mt][nt][r];
                int col = bn + wn * 64 + nt * 16 + c15;
                if (v > bv) { bv = v; bi = col; }
            }
            #pragma unroll
            for (int m = 1; m < 16; m <<= 1) {
                float ov = __shfl_xor(bv, m, 64);
                int   oi = __shfl_xor(bi, m, 64);
                if (ov > bv || (ov == bv && oi < bi)) { bv = ov; bi = oi; }
            }
            if (c15 == 0) {
                int row = wm * 64 + mt * 16 + quad * 4 + r;
                redv[row][wn] = bv; redi[row][wn] = bi;
            }
        }
    __syncthreads();
    if (tid < 128) {
        float v0 = redv[tid][0], v1 = redv[tid][1];
        int   i0 = redi[tid][0], i1 = redi[tid][1];
        bool t = (v1 > v0) || (v1 == v0 && i1 < i0);
        pval[(size_t)blockIdx.x * 4096 + bm + tid] = t ? v1 : v0;
        pidx[(size_t)blockIdx.x * 4096 + bm + tid] = t ? i1 : i0;
    }
}

__global__ void simreduce_kernel(const float* __restrict__ pval, const int* __restrict__ pidx,
                                 float* __restrict__ bv, int* __restrict__ bi)
{
    const int n = blockIdx.x * 256 + threadIdx.x;
    float best = -1e30f; int besti = 0x7fffffff;
    for (int c = 0; c < 32; c++) {
        float v = pval[(size_t)c * 4096 + n]; int ix = pidx[(size_t)c * 4096 + n];
        if (v > best || (v == best && ix < besti)) { best = v; besti = ix; }
    }
    bv[n] = best; bi[n] = besti;
}

__global__ void zero2_kernel(float* p) { if (threadIdx.x < 2) p[threadIdx.x] = 0.f; }

// ===================== conversions =====================
// fp32 -> bf16 hi/lo split (flat, float4 per thread)
__global__ __launch_bounds__(256) void sconv_kernel(const float* __restrict__ s,
                                                    ushort* __restrict__ dh, ushort* __restrict__ dl)
{
    const int i = blockIdx.x * 256 + threadIdx.x;
    float4 v = ((const float4*)s)[i];
    ushort4 h, l;
    h.x = f2bf(v.x); l.x = f2bf(v.x - bf2f(h.x));
    h.y = f2bf(v.y); l.y = f2bf(v.y - bf2f(h.y));
    h.z = f2bf(v.z); l.z = f2bf(v.z - bf2f(h.z));
    h.w = f2bf(v.w); l.w = f2bf(v.w - bf2f(h.w));
    ((ushort4*)dh)[i] = h;
    ((ushort4*)dl)[i] = l;
}

// transpose fp32 [R][Cc] -> bf16 [Cc][R] (hi, optional lo)
__global__ __launch_bounds__(256) void wtrans_kernel(const float* __restrict__ src, int R, int Cc,
                                                     ushort* __restrict__ dh, ushort* __restrict__ dl)
{
    __shared__ float t[64][65];
    const int tid = threadIdx.x;
    const int c0 = blockIdx.x * 64, r0 = blockIdx.y * 64;
    #pragma unroll
    for (int i = 0; i < 16; i++) {
        int lin = i * 256 + tid;
        int rr = lin >> 6, cc = lin & 63;
        t[rr][cc] = src[(size_t)(r0 + rr) * Cc + c0 + cc];
    }
    __syncthreads();
    #pragma unroll
    for (int i = 0; i < 16; i++) {
        int lin = i * 256 + tid;
        int cc2 = lin >> 6, rr2 = lin & 63;
        float v = t[rr2][cc2];
        ushort h = f2bf(v);
        dh[(size_t)(c0 + cc2) * R + r0 + rr2] = h;
        if (dl) dl[(size_t)(c0 + cc2) * R + r0 + rr2] = f2bf(v - bf2f(h));
    }
}

// q: mh_rms + split + [h][n][d] layout. one wave per (n,h)
__global__ __launch_bounds__(256) void qconv_kernel(const float* __restrict__ QKV,
                                                    const float* __restrict__ gamma_q,
                                                    ushort* __restrict__ Qh, ushort* __restrict__ Ql)
{
    const int wg = blockIdx.x * 4 + (threadIdx.x >> 6);
    const int lane = threadIdx.x & 63;
    const int n = wg >> 4, h = wg & 15;
    float x = QKV[(size_t)n * 3072 + h * 64 + lane];
    float ss = x * x;
    #pragma unroll
    for (int off = 32; off; off >>= 1) ss += __shfl_xor(ss, off, 64);
    float v = x * (8.0f * gamma_q[h * 64 + lane] / fmaxf(sqrtf(ss), 1e-12f));
    ushort hh = f2bf(v);
    size_t o = ((size_t)h * 4096 + n) * 64 + lane;
    Qh[o] = hh; Ql[o] = f2bf(v - bf2f(hh));
}

// l2-normalize row (D=1024) -> bf16. one block per row
__global__ __launch_bounds__(256) void kbn_kernel(const float* __restrict__ src, int ld,
                                                  ushort* __restrict__ dst)
{
    const int n = blockIdx.x, t = threadIdx.x;
    float4 v = *(const float4*)(src + (size_t)n * ld + 4 * t);
    float ss = v.x * v.x + v.y * v.y + v.z * v.z + v.w * v.w;
    #pragma unroll
    for (int off = 32; off; off >>= 1) ss += __shfl_xor(ss, off, 64);
    __shared__ float wsum[4];
    if ((t & 63) == 0) wsum[t >> 6] = ss;
    __syncthreads();
    float inv = 1.0f / fmaxf(sqrtf(wsum[0] + wsum[1] + wsum[2] + wsum[3]), 1e-12f);
    ushort4 o;
    o.x = f2bf(v.x * inv); o.y = f2bf(v.y * inv);
    o.z = f2bf(v.z * inv); o.w = f2bf(v.w * inv);
    *(ushort4*)(dst + (size_t)n * 1024 + 4 * t) = o;
}

// combine + per-head mh_rms(k) -> CKb split [16][4096][64]; CV fp32 + sumsqs
__global__ __launch_bounds__(256) void combine_kernel(
    const float* __restrict__ QKV,
    const float* __restrict__ k0, const float* __restrict__ v0,
    const float* __restrict__ k1, const float* __restrict__ v1,
    const float* __restrict__ bv0, const int* __restrict__ bi0,
    const float* __restrict__ bv1, const int* __restrict__ bi1,
    const float* __restrict__ gamma_k,
    ushort* __restrict__ CKh, ushort* __restrict__ CKl,
    float* __restrict__ CV, float* __restrict__ ss)
{
    const int n = blockIdx.x, t = threadIdx.x;
    const bool va0 = bv0[n] > TAU_F; const int i0 = bi0[n];
    const bool va1 = bv1[n] > TAU_F; const int i1 = bi1[n];
    float4 kf = ((const float4*)(QKV + (size_t)n * 3072 + 1024))[t];
    float4 vf = ((const float4*)(QKV + (size_t)n * 3072 + 2048))[t];
    float4 kg0 = va0 ? ((const float4*)(k0 + (size_t)i0 * 1024))[t] : kf;
    float4 vg0 = va0 ? ((const float4*)(v0 + (size_t)i0 * 1024))[t] : vf;
    float4 kg1 = va1 ? ((const float4*)(k1 + (size_t)i1 * 1024))[t] : kf;
    float4 vg1 = va1 ? ((const float4*)(v1 + (size_t)i1 * 1024))[t] : vf;
    float4 ck, cv;
    ck.x = 0.5f * kg0.x + 0.5f * kg1.x + kf.x;
    ck.y = 0.5f * kg0.y + 0.5f * kg1.y + kf.y;
    ck.z = 0.5f * kg0.z + 0.5f * kg1.z + kf.z;
    ck.w = 0.5f * kg0.w + 0.5f * kg1.w + kf.w;
    cv.x = 0.5f * vg0.x + 0.5f * vg1.x + vf.x;
    cv.y = 0.5f * vg0.y + 0.5f * vg1.y + vf.y;
    cv.z = 0.5f * vg0.z + 0.5f * vg1.z + vf.z;
    cv.w = 0.5f * vg0.w + 0.5f * vg1.w + vf.w;
    ((float4*)(CV + (size_t)n * 1024))[t] = cv;
    // v sumsqs
    float s0 = vf.x * vf.x + vf.y * vf.y + vf.z * vf.z + vf.w * vf.w;
    float s1 = cv.x * cv.x + cv.y * cv.y + cv.z * cv.z + cv.w * cv.w;
    #pragma unroll
    for (int off = 32; off; off >>= 1) {
        s0 += __shfl_xor(s0, off, 64);
        s1 += __shfl_xor(s1, off, 64);
    }
    __shared__ float w0[4], w1[4];
    if ((t & 63) == 0) { w0[t >> 6] = s0; w1[t >> 6] = s1; }
    // per-head rms of ck (16 threads per head; sk cancels analytically)
    float hs = ck.x * ck.x + ck.y * ck.y + ck.z * ck.z + ck.w * ck.w;
    #pragma unroll
    for (int m = 1; m < 16; m <<= 1) hs += __shfl_xor(hs, m, 64);
    float inv = 8.0f / fmaxf(sqrtf(hs), 1e-12f);
    float4 g = ((const float4*)gamma_k)[t];   // gamma flat index 4t == h*64 + 4*(t&15)
    const int h = t >> 4;
    size_t o = ((size_t)h * 4096 + n) * 64 + 4 * (t & 15);
    float a0 = ck.x * inv * g.x, a1 = ck.y * inv * g.y;
    float a2 = ck.z * inv * g.z, a3 = ck.w * inv * g.w;
    ushort4 hh, ll;
    hh.x = f2bf(a0); ll.x = f2bf(a0 - bf2f(hh.x));
    hh.y = f2bf(a1); ll.y = f2bf(a1 - bf2f(hh.y));
    hh.z = f2bf(a2); ll.z = f2bf(a2 - bf2f(hh.z));
    hh.w = f2bf(a3); ll.w = f2bf(a3 - bf2f(hh.w));
    *(ushort4*)(CKh + o) = hh;
    *(ushort4*)(CKl + o) = ll;
    __syncthreads();
    if (t == 0) {
        atomicAdd(ss + 0, w0[0] + w0[1] + w0[2] + w0[3]);
        atomicAdd(ss + 1, w1[0] + w1[1] + w1[2] + w1[3]);
    }
}

// CV fp32 [4096][1024] --(*sv)--> Vt bf16 [1024][4096] (single rounding)
__global__ __launch_bounds__(256) void vt_kernel(const float* __restrict__ CV,
                                                 const float* __restrict__ ss,
                                                 ushort* __restrict__ Vt)
{
    __shared__ float t[64][65];
    const float sv = sqrtf(ss[0] / ss[1]);
    const int tid = threadIdx.x;
    const int n0 = blockIdx.x * 64, d0 = blockIdx.y * 64;
    #pragma unroll
    for (int i = 0; i < 16; i++) {
        int lin = i * 256 + tid;
        int r = lin >> 6, c = lin & 63;
        t[r][c] = CV[(size_t)(n0 + r) * 1024 + d0 + c];
    }
    __syncthreads();
    #pragma unroll
    for (int i = 0; i < 16; i++) {
        int lin = i * 256 + tid;
        int dr = lin >> 6, nc = lin & 63;
        Vt[(size_t)(d0 + dr) * 4096 + n0 + nc] = f2bf(t[nc][dr] * sv);
    }
}

// ===================== flash attention, MFMA =====================
// grid (32 q-tiles, 16 heads), 256 threads (4 waves, 32 q-rows each)
__global__ __launch_bounds__(256) void attn_mfma(
    const ushort* __restrict__ Qh, const ushort* __restrict__ Ql,   // [16][4096][64]
    const ushort* __restrict__ Kh, const ushort* __restrict__ Kl,   // [16][4096][64]
    const ushort* __restrict__ Vt,                                  // [1024][4096]
    ushort* __restrict__ Hb)                                        // [4096][1024]
{
    __shared__ __align__(16) ushort Ks_h[128 * 64];
    __shared__ __align__(16) ushort Ks_l[128 * 64];
    __shared__ __align__(16) ushort Vs[64 * 128];
    __shared__ __align__(16) ushort Ps[128 * 128];
    const int h = blockIdx.y;
    const int n0 = blockIdx.x * 128;
    const int tid = threadIdx.x;
    const int w = tid >> 6, lane = tid & 63;
    const int quad = lane >> 4, c15 = lane & 15;
    const int rw = w * 32;

    // Q fragments from global (A-operand layout), hi+lo
    short8 qh[2][2], ql[2][2];
    #pragma unroll
    for (int mt = 0; mt < 2; mt++)
        #pragma unroll
        for (int kh = 0; kh < 2; kh++) {
            size_t o = ((size_t)h * 4096 + n0 + rw + mt * 16 + c15) * 64 + kh * 32 + quad * 8;
            qh[mt][kh] = *(const short8*)(Qh + o);
            ql[mt][kh] = *(const short8*)(Ql + o);
        }

    floatx4 po[2][4];
    #pragma unroll
    for (int mt = 0; mt < 2; mt++)
        #pragma unroll
        for (int nt = 0; nt < 4; nt++) po[mt][nt] = (floatx4){0.f, 0.f, 0.f, 0.f};
    float mst[2][4], lst[2][4];
    #pragma unroll
    for (int mt = 0; mt < 2; mt++)
        #pragma unroll
        for (int r = 0; r < 4; r++) { mst[mt][r] = -1e30f; lst[mt][r] = 0.f; }

    for (int it = 0; it < 32; ++it) {
        const int m0 = it * 128;
        // stage K (hi,lo): contiguous 16KB each; V^T: 64 rows x 256B
        stage_swz<8, 16>(Ks_h, (const char*)(Kh + ((size_t)h * 4096 + m0) * 64), 128, w, lane);
        stage_swz<8, 16>(Ks_l, (const char*)(Kl + ((size_t)h * 4096 + m0) * 64), 128, w, lane);
        stage_swz<16, 16>(Vs, (const char*)(Vt + (size_t)h * 64 * 4096 + m0), 8192, w, lane);
        __syncthreads();

        // S = Q K^T (split QK: hh + hl + lh)
        floatx4 s[2][8];
        #pragma unroll
        for (int mt = 0; mt < 2; mt++)
            #pragma unroll
            for (int nt = 0; nt < 8; nt++) s[mt][nt] = (floatx4){0.f, 0.f, 0.f, 0.f};
        #pragma unroll
        for (int nt = 0; nt < 8; nt++) {
            int row = nt * 16 + c15;
            short8 kh0 = *(const short8*)&Ks_h[row * 64 + swz(row, quad, 7) * 8];
            short8 kh1 = *(const short8*)&Ks_h[row * 64 + swz(row, 4 + quad, 7) * 8];
            short8 kl0 = *(const short8*)&Ks_l[row * 64 + swz(row, quad, 7) * 8];
            short8 kl1 = *(const short8*)&Ks_l[row * 64 + swz(row, 4 + quad, 7) * 8];
            #pragma unroll
            for (int mt = 0; mt < 2; mt++) {
                s[mt][nt] = __builtin_amdgcn_mfma_f32_16x16x32_bf16(qh[mt][0], kh0, s[mt][nt], 0, 0, 0);
                s[mt][nt] = __builtin_amdgcn_mfma_f32_16x16x32_bf16(qh[mt][1], kh1, s[mt][nt], 0, 0, 0);
                s[mt][nt] = __builtin_amdgcn_mfma_f32_16x16x32_bf16(qh[mt][0], kl0, s[mt][nt], 0, 0, 0);
                s[mt][nt] = __builtin_amdgcn_mfma_f32_16x16x32_bf16(qh[mt][1], kl1, s[mt][nt], 0, 0, 0);
                s[mt][nt] = __builtin_amdgcn_mfma_f32_16x16x32_bf16(ql[mt][0], kh0, s[mt][nt], 0, 0, 0);
                s[mt][nt] = __builtin_amdgcn_mfma_f32_16x16x32_bf16(ql[mt][1], kh1, s[mt][nt], 0, 0, 0);
            }
        }

        // online softmax (in-register, rows fully within wave's quad groups)
        const float sc = 0.125f;
        float alpha[2][4];
        #pragma unroll
        for (int mt = 0; mt < 2; mt++)
            #pragma unroll
            for (int r = 0; r < 4; r++) {
                float mx = s[mt][0][r];
                #pragma unroll
                for (int nt = 1; nt < 8; nt++) mx = fmaxf(mx, s[mt][nt][r]);
                #pragma unroll
                for (int m = 1; m < 16; m <<= 1) mx = fmaxf(mx, __shfl_xor(mx, m, 64));
                mx *= sc;
                float mn = fmaxf(mst[mt][r], mx);
                float al = __expf(mst[mt][r] - mn);
                mst[mt][r] = mn;
                int prow = rw + mt * 16 + quad * 4 + r;
                float ls = 0.f;
                #pragma unroll
                for (int nt = 0; nt < 8; nt++) {
                    float p = __expf(s[mt][nt][r] * sc - mn);
                    ls += p;
                    int k = nt * 16 + c15;
                    int j = k >> 3;
                    Ps[prow * 128 + swz(prow, j, 15) * 8 + (k & 7)] = f2bf(p);
                }
                #pragma unroll
                for (int m = 1; m < 16; m <<= 1) ls += __shfl_xor(ls, m, 64);
                lst[mt][r] = lst[mt][r] * al + ls;
                alpha[mt][r] = al;
            }
        // rescale O
        #pragma unroll
        for (int mt = 0; mt < 2; mt++)
            #pragma unroll
            for (int nt = 0; nt < 4; nt++)
                #pragma unroll
                for (int r = 0; r < 4; r++) po[mt][nt][r] *= alpha[mt][r];

        // O += P V
        #pragma unroll
        for (int kb = 0; kb < 4; kb++) {
            short8 pa[2];
            #pragma unroll
            for (int mt = 0; mt < 2; mt++) {
                int prow = rw + mt * 16 + c15;
                pa[mt] = *(const short8*)&Ps[prow * 128 + swz(prow, kb * 4 + quad, 15) * 8];
            }
            #pragma unroll
            for (int nt = 0; nt < 4; nt++) {
                int drow = nt * 16 + c15;
                short8 vb = *(const short8*)&Vs[drow * 128 + swz(drow, kb * 4 + quad, 15) * 8];
                #pragma unroll
                for (int mt = 0; mt < 2; mt++)
                    po[mt][nt] = __builtin_amdgcn_mfma_f32_16x16x32_bf16(pa[mt], vb, po[mt][nt], 0, 0, 0);
            }
        }
        __syncthreads();
    }
    // epilogue: O/l -> bf16 Hb
    #pragma unroll
    for (int mt = 0; mt < 2; mt++)
        #pragma unroll
        for (int r = 0; r < 4; r++) {
            float inv = 1.0f / lst[mt][r];
            int row = n0 + rw + mt * 16 + quad * 4 + r;
            #pragma unroll
            for (int nt = 0; nt < 4; nt++)
                Hb[(size_t)row * 1024 + h * 64 + nt * 16 + c15] = f2bf(po[mt][nt][r] * inv);
        }
}

// ===================== launcher =====================
extern "C" void kernel_launch(void* const* d_in, const int* in_sizes, int n_in,
                              void* d_out, int out_size, void* d_ws, size_t ws_size,
                              hipStream_t stream)
{
    const float* x       = (const float*)d_in[0];
    const float* k0      = (const float*)d_in[1];
    const float* v0      = (const float*)d_in[2];
    const float* k1      = (const float*)d_in[3];
    const float* v1      = (const float*)d_in[4];
    const float* W_qkv   = (const float*)d_in[5];
    const float* b_qkv   = (const float*)d_in[6];
    const float* gamma_q = (const float*)d_in[7];
    const float* gamma_k = (const float*)d_in[8];
    const float* W_out   = (const float*)d_in[9];
    const float* b_out   = (const float*)d_in[10];
    float* out = (float*)d_out;

    char* W = (char*)d_ws;
    // Region A (0..48M): QKV fp32; after combine reused for Vt + Hb
    float*  QKV = (float*)(W + 0);
    ushort* Vt  = (ushort*)(W + 0);
    ushort* Hb  = (ushort*)(W + 8388608);
    // Region B (48M..64M): Qb split
    ushort* Qbh = (ushort*)(W + 50331648);
    ushort* Qbl = (ushort*)(W + 50331648 + 8388608);
    // Region C (64M..96M): phased
    ushort* xh   = (ushort*)(W + 67108864);
    ushort* xl   = (ushort*)(W + 67108864 + 8388608);
    ushort* Wqh  = (ushort*)(W + 67108864 + 16777216);
    ushort* Wql  = (ushort*)(W + 67108864 + 23068672);
    ushort* kbn  = (ushort*)(W + 67108864);
    ushort* k0bn = (ushort*)(W + 67108864 + 8388608);
    ushort* k1bn = (ushort*)(W + 67108864 + 16777216);
    float*  pval0= (float*)(W + 67108864 + 25165824);
    int*    pidx0= (int*)  (W + 67108864 + 25690112);
    float*  pval1= (float*)(W + 67108864 + 26214400);
    int*    pidx1= (int*)  (W + 67108864 + 26738688);
    float*  CV   = (float*)(W + 67108864);
    ushort* CKh  = (ushort*)(W + 67108864 + 16777216);
    ushort* CKl  = (ushort*)(W + 67108864 + 25165824);
    ushort* Wob  = (ushort*)(W + 67108864);
    // Region D (96M..): small
    float* bv0  = (float*)(W + 100663296);
    int*   bi0  = (int*)  (W + 100663296 + 16384);
    float* bv1  = (float*)(W + 100663296 + 32768);
    int*   bi1  = (int*)  (W + 100663296 + 49152);
    float* ssum = (float*)(W + 100663296 + 65536);

    // 1. convert inputs for QKV GEMM
    sconv_kernel<<<4096, 256, 0, stream>>>(x, xh, xl);
    wtrans_kernel<<<dim3(48, 16), 256, 0, stream>>>(W_qkv, 1024, 3072, Wqh, Wql);
    // 2. QKV = x @ W_qkv + b  (split bf16, fp32-grade)
    gemm_nt_kernel<true><<<dim3(24, 32), 256, 0, stream>>>(xh, xl, 1024, Wqh, Wql, 1024,
                                                           b_qkv, QKV, 3072, 1024);
    // 3. q -> mh_rms -> Qb split [h][n][d]
    qconv_kernel<<<16384, 256, 0, stream>>>(QKV, gamma_q, Qbh, Qbl);
    // 4. normalized bf16 copies for sim
    kbn_kernel<<<4096, 256, 0, stream>>>(QKV + 1024, 3072, kbn);
    kbn_kernel<<<4096, 256, 0, stream>>>(k0, 1024, k0bn);
    kbn_kernel<<<4096, 256, 0, stream>>>(k1, 1024, k1bn);
    // 5. sim + top-1 (bf16 MFMA, fused argmax)
    simmax_mfma<<<dim3(32, 32), 256, 0, stream>>>(kbn, k0bn, pval0, pidx0);
    simmax_mfma<<<dim3(32, 32), 256, 0, stream>>>(kbn, k1bn, pval1, pidx1);
    simreduce_kernel<<<16, 256, 0, stream>>>(pval0, pidx0, bv0, bi0);
    simreduce_kernel<<<16, 256, 0, stream>>>(pval1, pidx1, bv1, bi1);
    // 6. combine (+mh_rms k fused; sk cancels) -> CKb split, CV fp32, sumsqs
    zero2_kernel<<<1, 64, 0, stream>>>(ssum);
    combine_kernel<<<4096, 256, 0, stream>>>(QKV, k0, v0, k1, v1, bv0, bi0, bv1, bi1,
                                             gamma_k, CKh, CKl, CV, ssum);
    // 7. V: scale by sv + transpose -> Vt bf16 [1024][4096]
    vt_kernel<<<dim3(64, 16), 256, 0, stream>>>(CV, ssum, Vt);
    // 8. W_out transpose -> bf16 (plain)
    wtrans_kernel<<<dim3(16, 16), 256, 0, stream>>>(W_out, 1024, 1024, Wob, nullptr);
    // 9. flash attention (MFMA, split QK, plain PV)
    attn_mfma<<<dim3(32, 16), 256, 0, stream>>>(Qbh, Qbl, CKh, CKl, Vt, Hb);
    // 10. out = Hb @ W_out^T + b_out (plain bf16)
    gemm_nt_kernel<false><<<dim3(8, 32), 256, 0, stream>>>(Hb, nullptr, 1024, Wob, nullptr, 1024,
                                                           b_out, out, 1024, 1024);
}

// Round 3
// 714.122 us; speedup vs baseline: 5.2040x; 1.2558x over previous
//
#include <hip/hip_runtime.h>
#include <math.h>

#define TAU_F 0.6f

typedef short short8 __attribute__((ext_vector_type(8)));
typedef float floatx4 __attribute__((ext_vector_type(4)));

__device__ __forceinline__ ushort f2bf(float f) {
    unsigned u = __float_as_uint(f);
    u += 0x7FFF + ((u >> 16) & 1);
    return (ushort)(u >> 16);
}
__device__ __forceinline__ float bf2f(ushort h) {
    return __uint_as_float(((unsigned)h) << 16);
}
__device__ __forceinline__ int swz(int row, int j, int mask) { return j ^ (row & mask); }

// Stage a tile from global into LDS with XOR-chunk swizzle via global_load_lds (16B).
// SC = number of 1KB superchunks; CPR = 16B chunks per row.
template<int CPR, int SC>
__device__ __forceinline__ void stage_swz(ushort* lds, const char* g, int rowstride_bytes,
                                          int w, int lane)
{
    #pragma unroll
    for (int p = 0; p < (SC + 3) / 4; ++p) {
        int sc = w + p * 4;
        if (SC % 4 != 0 && sc >= SC) break;
        int LC = sc * 64 + lane;          // 16B lane-chunk index
        int r = LC / CPR;
        int s = LC % CPR;
        int j = s ^ (r & (CPR - 1));
        const char* gp = g + (size_t)r * rowstride_bytes + j * 16;
        __builtin_amdgcn_global_load_lds(
            (const __attribute__((address_space(1))) void*)gp,
            (__attribute__((address_space(3))) void*)((char*)lds + sc * 1024), 16, 0, 0);
    }
}

// ===================== MFMA NT GEMM: C[M,N] = A[M,K] * Bt[N,K]^T + bias =====================
template<bool SPLIT>
__global__ __launch_bounds__(256) void gemm_nt_kernel(
    const ushort* __restrict__ Ah, const ushort* __restrict__ Al, int lda,
    const ushort* __restrict__ Bh, const ushort* __restrict__ Bl, int ldb,
    const float* __restrict__ bias, float* __restrict__ C, int ldc, int K)
{
    __shared__ __align__(16) ushort As_h[128 * 32];
    __shared__ __align__(16) ushort Bs_h[128 * 32];
    __shared__ __align__(16) ushort As_l[128 * 32];
    __shared__ __align__(16) ushort Bs_l[128 * 32];
    const int tid = threadIdx.x;
    const int w = tid >> 6, lane = tid & 63;
    const int quad = lane >> 4, c15 = lane & 15;
    const int wm = w >> 1, wn = w & 1;
    const int bm = blockIdx.y * 128, bn = blockIdx.x * 128;

    floatx4 acc[4][4];
    #pragma unroll
    for (int i = 0; i < 4; i++)
        #pragma unroll
        for (int j = 0; j < 4; j++) acc[i][j] = (floatx4){0.f, 0.f, 0.f, 0.f};

    const char* Ab = (const char*)(Ah + (size_t)bm * lda);
    const char* Bb = (const char*)(Bh + (size_t)bn * ldb);
    const char* Alb = SPLIT ? (const char*)(Al + (size_t)bm * lda) : nullptr;
    const char* Blb = SPLIT ? (const char*)(Bl + (size_t)bn * ldb) : nullptr;

    for (int k0 = 0; k0 < K; k0 += 32) {
        stage_swz<4, 8>(As_h, Ab + k0 * 2, lda * 2, w, lane);
        stage_swz<4, 8>(Bs_h, Bb + k0 * 2, ldb * 2, w, lane);
        if constexpr (SPLIT) {
            stage_swz<4, 8>(As_l, Alb + k0 * 2, lda * 2, w, lane);
            stage_swz<4, 8>(Bs_l, Blb + k0 * 2, ldb * 2, w, lane);
        }
        __syncthreads();
        short8 a_h[4], b_h[4], a_l[4], b_l[4];
        #pragma unroll
        for (int mt = 0; mt < 4; mt++) {
            int row = wm * 64 + mt * 16 + c15;
            a_h[mt] = *(const short8*)&As_h[row * 32 + swz(row, quad, 3) * 8];
            if constexpr (SPLIT)
                a_l[mt] = *(const short8*)&As_l[row * 32 + swz(row, quad, 3) * 8];
        }
        #pragma unroll
        for (int nt = 0; nt < 4; nt++) {
            int row = wn * 64 + nt * 16 + c15;
            b_h[nt] = *(const short8*)&Bs_h[row * 32 + swz(row, quad, 3) * 8];
            if constexpr (SPLIT)
                b_l[nt] = *(const short8*)&Bs_l[row * 32 + swz(row, quad, 3) * 8];
        }
        #pragma unroll
        for (int mt = 0; mt < 4; mt++)
            #pragma unroll
            for (int nt = 0; nt < 4; nt++)
                acc[mt][nt] = __builtin_amdgcn_mfma_f32_16x16x32_bf16(a_h[mt], b_h[nt], acc[mt][nt], 0, 0, 0);
        if constexpr (SPLIT) {
            #pragma unroll
            for (int mt = 0; mt < 4; mt++)
                #pragma unroll
                for (int nt = 0; nt < 4; nt++)
                    acc[mt][nt] = __builtin_amdgcn_mfma_f32_16x16x32_bf16(a_h[mt], b_l[nt], acc[mt][nt], 0, 0, 0);
            #pragma unroll
            for (int mt = 0; mt < 4; mt++)
                #pragma unroll
                for (int nt = 0; nt < 4; nt++)
                    acc[mt][nt] = __builtin_amdgcn_mfma_f32_16x16x32_bf16(a_l[mt], b_h[nt], acc[mt][nt], 0, 0, 0);
        }
        __syncthreads();
    }
    #pragma unroll
    for (int mt = 0; mt < 4; mt++)
        #pragma unroll
        for (int nt = 0; nt < 4; nt++) {
            int col = bn + wn * 64 + nt * 16 + c15;
            float bs = bias ? bias[col] : 0.f;
            #pragma unroll
            for (int r = 0; r < 4; r++) {
                int row = bm + wm * 64 + mt * 16 + quad * 4 + r;
                C[(size_t)row * ldc + col] = acc[mt][nt][r] + bs;
            }
        }
}

// ===================== sim GEMM (bf16) with fused per-row max/argmax =====================
// B covers 8192 rows (k0bn || k1bn). grid (64, 32).
__global__ __launch_bounds__(256) void simmax_mfma(
    const ushort* __restrict__ A, const ushort* __restrict__ B,
    float* __restrict__ pval, int* __restrict__ pidx)
{
    __shared__ __align__(16) ushort As_h[128 * 32];
    __shared__ __align__(16) ushort Bs_h[128 * 32];
    __shared__ float redv[128][2];
    __shared__ int   redi[128][2];
    const int tid = threadIdx.x;
    const int w = tid >> 6, lane = tid & 63;
    const int quad = lane >> 4, c15 = lane & 15;
    const int wm = w >> 1, wn = w & 1;
    const int bm = blockIdx.y * 128, bn = blockIdx.x * 128;

    floatx4 acc[4][4];
    #pragma unroll
    for (int i = 0; i < 4; i++)
        #pragma unroll
        for (int j = 0; j < 4; j++) acc[i][j] = (floatx4){0.f, 0.f, 0.f, 0.f};

    const char* Ab = (const char*)(A + (size_t)bm * 1024);
    const char* Bb = (const char*)(B + (size_t)bn * 1024);

    for (int k0 = 0; k0 < 1024; k0 += 32) {
        stage_swz<4, 8>(As_h, Ab + k0 * 2, 2048, w, lane);
        stage_swz<4, 8>(Bs_h, Bb + k0 * 2, 2048, w, lane);
        __syncthreads();
        short8 a_h[4], b_h[4];
        #pragma unroll
        for (int mt = 0; mt < 4; mt++) {
            int row = wm * 64 + mt * 16 + c15;
            a_h[mt] = *(const short8*)&As_h[row * 32 + swz(row, quad, 3) * 8];
        }
        #pragma unroll
        for (int nt = 0; nt < 4; nt++) {
            int row = wn * 64 + nt * 16 + c15;
            b_h[nt] = *(const short8*)&Bs_h[row * 32 + swz(row, quad, 3) * 8];
        }
        #pragma unroll
        for (int mt = 0; mt < 4; mt++)
            #pragma unroll
            for (int nt = 0; nt < 4; nt++)
                acc[mt][nt] = __builtin_amdgcn_mfma_f32_16x16x32_bf16(a_h[mt], b_h[nt], acc[mt][nt], 0, 0, 0);
        __syncthreads();
    }
    #pragma unroll
    for (int mt = 0; mt < 4; mt++)
        #pragma unroll
        for (int r = 0; r < 4; r++) {
            float bv = -1e30f; int bi = 0;
            #pragma unroll
            for (int nt = 0; nt < 4; nt++) {
                float v = acc[mt][nt][r];
                int col = bn + wn * 64 + nt * 16 + c15;
                if (v > bv) { bv = v; bi = col; }
            }
            #pragma unroll
            for (int m = 1; m < 16; m <<= 1) {
                float ov = __shfl_xor(bv, m, 64);
                int   oi = __shfl_xor(bi, m, 64);
                if (ov > bv || (ov == bv && oi < bi)) { bv = ov; bi = oi; }
            }
            if (c15 == 0) {
                int row = wm * 64 + mt * 16 + quad * 4 + r;
                redv[row][wn] = bv; redi[row][wn] = bi;
            }
        }
    __syncthreads();
    if (tid < 128) {
        float v0 = redv[tid][0], v1 = redv[tid][1];
        int   i0 = redi[tid][0], i1 = redi[tid][1];
        bool t = (v1 > v0) || (v1 == v0 && i1 < i0);
        pval[(size_t)blockIdx.x * 4096 + bm + tid] = t ? v1 : v0;
        pidx[(size_t)blockIdx.x * 4096 + bm + tid] = t ? i1 : i0;
    }
}

// fused reduce for both halves (chunks 0..31 = k0, 32..63 = k1)
__global__ void simreduce2_kernel(const float* __restrict__ pval, const int* __restrict__ pidx,
                                  float* __restrict__ bv0, int* __restrict__ bi0,
                                  float* __restrict__ bv1, int* __restrict__ bi1)
{
    const int n = blockIdx.x * 256 + threadIdx.x;
    float best = -1e30f; int besti = 0x7fffffff;
    for (int c = 0; c < 32; c++) {
        float v = pval[(size_t)c * 4096 + n]; int ix = pidx[(size_t)c * 4096 + n];
        if (v > best || (v == best && ix < besti)) { best = v; besti = ix; }
    }
    bv0[n] = best; bi0[n] = besti;
    best = -1e30f; besti = 0x7fffffff;
    for (int c = 32; c < 64; c++) {
        float v = pval[(size_t)c * 4096 + n]; int ix = pidx[(size_t)c * 4096 + n];
        if (v > best || (v == best && ix < besti)) { best = v; besti = ix; }
    }
    bv1[n] = best; bi1[n] = besti - 4096;
}

__global__ void zero2_kernel(float* p) { if (threadIdx.x < 2) p[threadIdx.x] = 0.f; }

// ===================== conversions =====================
__global__ __launch_bounds__(256) void sconv_kernel(const float* __restrict__ s,
                                                    ushort* __restrict__ dh, ushort* __restrict__ dl)
{
    const int i = blockIdx.x * 256 + threadIdx.x;
    float4 v = ((const float4*)s)[i];
    ushort4 h, l;
    h.x = f2bf(v.x); l.x = f2bf(v.x - bf2f(h.x));
    h.y = f2bf(v.y); l.y = f2bf(v.y - bf2f(h.y));
    h.z = f2bf(v.z); l.z = f2bf(v.z - bf2f(h.z));
    h.w = f2bf(v.w); l.w = f2bf(v.w - bf2f(h.w));
    ((ushort4*)dh)[i] = h;
    ((ushort4*)dl)[i] = l;
}

__global__ __launch_bounds__(256) void wtrans_kernel(const float* __restrict__ src, int R, int Cc,
                                                     ushort* __restrict__ dh, ushort* __restrict__ dl)
{
    __shared__ float t[64][65];
    const int tid = threadIdx.x;
    const int c0 = blockIdx.x * 64, r0 = blockIdx.y * 64;
    #pragma unroll
    for (int i = 0; i < 16; i++) {
        int lin = i * 256 + tid;
        int rr = lin >> 6, cc = lin & 63;
        t[rr][cc] = src[(size_t)(r0 + rr) * Cc + c0 + cc];
    }
    __syncthreads();
    #pragma unroll
    for (int i = 0; i < 16; i++) {
        int lin = i * 256 + tid;
        int cc2 = lin >> 6, rr2 = lin & 63;
        float v = t[rr2][cc2];
        ushort h = f2bf(v);
        dh[(size_t)(c0 + cc2) * R + r0 + rr2] = h;
        if (dl) dl[(size_t)(c0 + cc2) * R + r0 + rr2] = f2bf(v - bf2f(h));
    }
}

// q: mh_rms + split + [h][n][d] layout. one wave per (n,h)
__global__ __launch_bounds__(256) void qconv_kernel(const float* __restrict__ QKV,
                                                    const float* __restrict__ gamma_q,
                                                    ushort* __restrict__ Qh, ushort* __restrict__ Ql)
{
    const int wg = blockIdx.x * 4 + (threadIdx.x >> 6);
    const int lane = threadIdx.x & 63;
    const int n = wg >> 4, h = wg & 15;
    float x = QKV[(size_t)n * 3072 + h * 64 + lane];
    float ss = x * x;
    #pragma unroll
    for (int off = 32; off; off >>= 1) ss += __shfl_xor(ss, off, 64);
    float v = x * (8.0f * gamma_q[h * 64 + lane] / fmaxf(sqrtf(ss), 1e-12f));
    ushort hh = f2bf(v);
    size_t o = ((size_t)h * 4096 + n) * 64 + lane;
    Qh[o] = hh; Ql[o] = f2bf(v - bf2f(hh));
}

// l2-normalize rows -> bf16, three sources in one launch. grid (4096, 3)
__global__ __launch_bounds__(256) void kbn3_kernel(const float* __restrict__ QKV,
                                                   const float* __restrict__ k0,
                                                   const float* __restrict__ k1,
                                                   ushort* __restrict__ kbn,
                                                   ushort* __restrict__ k01bn)
{
    const int n = blockIdx.x, t = threadIdx.x, y = blockIdx.y;
    const float* src; int ld; ushort* dst;
    if (y == 0)      { src = QKV + 1024; ld = 3072; dst = kbn; }
    else if (y == 1) { src = k0; ld = 1024; dst = k01bn; }
    else             { src = k1; ld = 1024; dst = k01bn + (size_t)4096 * 1024; }
    float4 v = *(const float4*)(src + (size_t)n * ld + 4 * t);
    float ss = v.x * v.x + v.y * v.y + v.z * v.z + v.w * v.w;
    #pragma unroll
    for (int off = 32; off; off >>= 1) ss += __shfl_xor(ss, off, 64);
    __shared__ float wsum[4];
    if ((t & 63) == 0) wsum[t >> 6] = ss;
    __syncthreads();
    float inv = 1.0f / fmaxf(sqrtf(wsum[0] + wsum[1] + wsum[2] + wsum[3]), 1e-12f);
    ushort4 o;
    o.x = f2bf(v.x * inv); o.y = f2bf(v.y * inv);
    o.z = f2bf(v.z * inv); o.w = f2bf(v.w * inv);
    *(ushort4*)(dst + (size_t)n * 1024 + 4 * t) = o;
}

// combine + per-head mh_rms(k) -> CKh [16][4096][64]; CV fp32 + sumsqs
__global__ __launch_bounds__(256) void combine_kernel(
    const float* __restrict__ QKV,
    const float* __restrict__ k0, const float* __restrict__ v0,
    const float* __restrict__ k1, const float* __restrict__ v1,
    const float* __restrict__ bv0, const int* __restrict__ bi0,
    const float* __restrict__ bv1, const int* __restrict__ bi1,
    const float* __restrict__ gamma_k,
    ushort* __restrict__ CKh,
    float* __restrict__ CV, float* __restrict__ ss)
{
    const int n = blockIdx.x, t = threadIdx.x;
    const bool va0 = bv0[n] > TAU_F; const int i0 = bi0[n];
    const bool va1 = bv1[n] > TAU_F; const int i1 = bi1[n];
    float4 kf = ((const float4*)(QKV + (size_t)n * 3072 + 1024))[t];
    float4 vf = ((const float4*)(QKV + (size_t)n * 3072 + 2048))[t];
    float4 kg0 = va0 ? ((const float4*)(k0 + (size_t)i0 * 1024))[t] : kf;
    float4 vg0 = va0 ? ((const float4*)(v0 + (size_t)i0 * 1024))[t] : vf;
    float4 kg1 = va1 ? ((const float4*)(k1 + (size_t)i1 * 1024))[t] : kf;
    float4 vg1 = va1 ? ((const float4*)(v1 + (size_t)i1 * 1024))[t] : vf;
    float4 ck, cv;
    ck.x = 0.5f * kg0.x + 0.5f * kg1.x + kf.x;
    ck.y = 0.5f * kg0.y + 0.5f * kg1.y + kf.y;
    ck.z = 0.5f * kg0.z + 0.5f * kg1.z + kf.z;
    ck.w = 0.5f * kg0.w + 0.5f * kg1.w + kf.w;
    cv.x = 0.5f * vg0.x + 0.5f * vg1.x + vf.x;
    cv.y = 0.5f * vg0.y + 0.5f * vg1.y + vf.y;
    cv.z = 0.5f * vg0.z + 0.5f * vg1.z + vf.z;
    cv.w = 0.5f * vg0.w + 0.5f * vg1.w + vf.w;
    ((float4*)(CV + (size_t)n * 1024))[t] = cv;
    float s0 = vf.x * vf.x + vf.y * vf.y + vf.z * vf.z + vf.w * vf.w;
    float s1 = cv.x * cv.x + cv.y * cv.y + cv.z * cv.z + cv.w * cv.w;
    #pragma unroll
    for (int off = 32; off; off >>= 1) {
        s0 += __shfl_xor(s0, off, 64);
        s1 += __shfl_xor(s1, off, 64);
    }
    __shared__ float w0[4], w1[4];
    if ((t & 63) == 0) { w0[t >> 6] = s0; w1[t >> 6] = s1; }
    // per-head rms of ck (16 threads per head; sk cancels analytically)
    float hs = ck.x * ck.x + ck.y * ck.y + ck.z * ck.z + ck.w * ck.w;
    #pragma unroll
    for (int m = 1; m < 16; m <<= 1) hs += __shfl_xor(hs, m, 64);
    float inv = 8.0f / fmaxf(sqrtf(hs), 1e-12f);
    float4 g = ((const float4*)gamma_k)[t];
    const int h = t >> 4;
    size_t o = ((size_t)h * 4096 + n) * 64 + 4 * (t & 15);
    ushort4 hh;
    hh.x = f2bf(ck.x * inv * g.x);
    hh.y = f2bf(ck.y * inv * g.y);
    hh.z = f2bf(ck.z * inv * g.z);
    hh.w = f2bf(ck.w * inv * g.w);
    *(ushort4*)(CKh + o) = hh;
    __syncthreads();
    if (t == 0) {
        atomicAdd(ss + 0, w0[0] + w0[1] + w0[2] + w0[3]);
        atomicAdd(ss + 1, w1[0] + w1[1] + w1[2] + w1[3]);
    }
}

// CV fp32 [4096][1024] --(*sv)--> Vt bf16 [1024][4096]
__global__ __launch_bounds__(256) void vt_kernel(const float* __restrict__ CV,
                                                 const float* __restrict__ ss,
                                                 ushort* __restrict__ Vt)
{
    __shared__ float t[64][65];
    const float sv = sqrtf(ss[0] / ss[1]);
    const int tid = threadIdx.x;
    const int n0 = blockIdx.x * 64, d0 = blockIdx.y * 64;
    #pragma unroll
    for (int i = 0; i < 16; i++) {
        int lin = i * 256 + tid;
        int r = lin >> 6, c = lin & 63;
        t[r][c] = CV[(size_t)(n0 + r) * 1024 + d0 + c];
    }
    __syncthreads();
    #pragma unroll
    for (int i = 0; i < 16; i++) {
        int lin = i * 256 + tid;
        int dr = lin >> 6, nc = lin & 63;
        Vt[(size_t)(d0 + dr) * 4096 + n0 + nc] = f2bf(t[nc][dr] * sv);
    }
}

// ===================== flash attention, MFMA, occupancy-optimized =====================
// grid (64 q-tiles, 16 heads), 256 threads = 4 waves, 16 q-rows each.
// K plain bf16 (error budget ok), Q split (registers only). 24 KB LDS.
__global__ __launch_bounds__(256) void attn_mfma(
    const ushort* __restrict__ Qh, const ushort* __restrict__ Ql,   // [16][4096][64]
    const ushort* __restrict__ Kh,                                  // [16][4096][64]
    const ushort* __restrict__ Vt,                                  // [1024][4096]
    ushort* __restrict__ Hb)                                        // [4096][1024]
{
    __shared__ __align__(16) ushort Ks[64 * 64];
    __shared__ __align__(16) ushort Vs[64 * 64];
    __shared__ __align__(16) ushort Ps[64 * 64];
    const int h = blockIdx.y;
    const int n0 = blockIdx.x * 64;
    const int tid = threadIdx.x;
    const int w = tid >> 6, lane = tid & 63;
    const int quad = lane >> 4, c15 = lane & 15;

    // Q fragments (A-operand layout), hi+lo, two 32-wide k-halves
    short8 qh[2], ql[2];
    #pragma unroll
    for (int kh = 0; kh < 2; kh++) {
        size_t o = ((size_t)h * 4096 + n0 + w * 16 + c15) * 64 + kh * 32 + quad * 8;
        qh[kh] = *(const short8*)(Qh + o);
        ql[kh] = *(const short8*)(Ql + o);
    }

    floatx4 po[4];
    #pragma unroll
    for (int nt = 0; nt < 4; nt++) po[nt] = (floatx4){0.f, 0.f, 0.f, 0.f};
    float mst[4], lst[4];
    #pragma unroll
    for (int r = 0; r < 4; r++) { mst[r] = -1e30f; lst[r] = 0.f; }

    for (int it = 0; it < 64; ++it) {
        const int m0 = it * 64;
        stage_swz<8, 8>(Ks, (const char*)(Kh + ((size_t)h * 4096 + m0) * 64), 128, w, lane);
        stage_swz<8, 8>(Vs, (const char*)(Vt + (size_t)h * 64 * 4096 + m0), 8192, w, lane);
        __syncthreads();

        // S = Q K^T (split Q: hh + lh)
        floatx4 s[4];
        #pragma unroll
        for (int nt = 0; nt < 4; nt++) {
            int row = nt * 16 + c15;
            short8 k0f = *(const short8*)&Ks[row * 64 + swz(row, quad, 7) * 8];
            short8 k1f = *(const short8*)&Ks[row * 64 + swz(row, 4 + quad, 7) * 8];
            floatx4 z = (floatx4){0.f, 0.f, 0.f, 0.f};
            z = __builtin_amdgcn_mfma_f32_16x16x32_bf16(qh[0], k0f, z, 0, 0, 0);
            z = __builtin_amdgcn_mfma_f32_16x16x32_bf16(qh[1], k1f, z, 0, 0, 0);
            z = __builtin_amdgcn_mfma_f32_16x16x32_bf16(ql[0], k0f, z, 0, 0, 0);
            z = __builtin_amdgcn_mfma_f32_16x16x32_bf16(ql[1], k1f, z, 0, 0, 0);
            s[nt] = z;
        }

        // online softmax (rows fully within this wave; Ps rows private to wave)
        const float sc = 0.125f;
        float alpha[4];
        #pragma unroll
        for (int r = 0; r < 4; r++) {
            float mx = s[0][r];
            #pragma unroll
            for (int nt = 1; nt < 4; nt++) mx = fmaxf(mx, s[nt][r]);
            #pragma unroll
            for (int m = 1; m < 16; m <<= 1) mx = fmaxf(mx, __shfl_xor(mx, m, 64));
            mx *= sc;
            float mn = fmaxf(mst[r], mx);
            float al = __expf(mst[r] - mn);
            mst[r] = mn;
            int prow = w * 16 + quad * 4 + r;
            float ls = 0.f;
            #pragma unroll
            for (int nt = 0; nt < 4; nt++) {
                float p = __expf(s[nt][r] * sc - mn);
                ls += p;
                int col = nt * 16 + c15;
                Ps[prow * 64 + swz(prow, col >> 3, 7) * 8 + (col & 7)] = f2bf(p);
            }
            #pragma unroll
            for (int m = 1; m < 16; m <<= 1) ls += __shfl_xor(ls, m, 64);
            lst[r] = lst[r] * al + ls;
            alpha[r] = al;
        }
        #pragma unroll
        for (int nt = 0; nt < 4; nt++)
            #pragma unroll
            for (int r = 0; r < 4; r++) po[nt][r] *= alpha[r];

        // O += P V
        #pragma unroll
        for (int kb = 0; kb < 2; kb++) {
            int prow2 = w * 16 + c15;
            short8 pa = *(const short8*)&Ps[prow2 * 64 + swz(prow2, kb * 4 + quad, 7) * 8];
            #pragma unroll
            for (int nt = 0; nt < 4; nt++) {
                int drow = nt * 16 + c15;
                short8 vb = *(const short8*)&Vs[drow * 64 + swz(drow, kb * 4 + quad, 7) * 8];
                po[nt] = __builtin_amdgcn_mfma_f32_16x16x32_bf16(pa, vb, po[nt], 0, 0, 0);
            }
        }
        __syncthreads();
    }
    #pragma unroll
    for (int r = 0; r < 4; r++) {
        float inv = 1.0f / lst[r];
        int row = n0 + w * 16 + quad * 4 + r;
        #pragma unroll
        for (int nt = 0; nt < 4; nt++)
            Hb[(size_t)row * 1024 + h * 64 + nt * 16 + c15] = f2bf(po[nt][r] * inv);
    }
}

// ===================== launcher =====================
extern "C" void kernel_launch(void* const* d_in, const int* in_sizes, int n_in,
                              void* d_out, int out_size, void* d_ws, size_t ws_size,
                              hipStream_t stream)
{
    const float* x       = (const float*)d_in[0];
    const float* k0      = (const float*)d_in[1];
    const float* v0      = (const float*)d_in[2];
    const float* k1      = (const float*)d_in[3];
    const float* v1      = (const float*)d_in[4];
    const float* W_qkv   = (const float*)d_in[5];
    const float* b_qkv   = (const float*)d_in[6];
    const float* gamma_q = (const float*)d_in[7];
    const float* gamma_k = (const float*)d_in[8];
    const float* W_out   = (const float*)d_in[9];
    const float* b_out   = (const float*)d_in[10];
    float* out = (float*)d_out;

    char* W = (char*)d_ws;
    // Region A (0..48M): QKV fp32; after combine reused for Vt + Hb
    float*  QKV = (float*)(W + 0);
    ushort* Vt  = (ushort*)(W + 0);
    ushort* Hb  = (ushort*)(W + 8388608);
    // Region B (48M..64M): Qb split
    ushort* Qbh = (ushort*)(W + 50331648);
    ushort* Qbl = (ushort*)(W + 50331648 + 8388608);
    // Region C (64M..96M): phased
    ushort* xh   = (ushort*)(W + 67108864);
    ushort* xl   = (ushort*)(W + 67108864 + 8388608);
    ushort* Wqh  = (ushort*)(W + 67108864 + 16777216);
    ushort* Wql  = (ushort*)(W + 67108864 + 23068672);
    ushort* kbn  = (ushort*)(W + 67108864);                 // 8 MB
    ushort* k01bn= (ushort*)(W + 67108864 + 8388608);       // 16 MB (k0||k1 contiguous)
    float*  pval = (float*)(W + 67108864 + 25165824);       // 1 MB
    int*    pidx = (int*)  (W + 67108864 + 26214400);       // 1 MB
    float*  CV   = (float*)(W + 67108864);                  // 16 MB
    ushort* CKh  = (ushort*)(W + 67108864 + 16777216);      // 8 MB (ends at 88M; pval/pidx live above)
    ushort* Wob  = (ushort*)(W + 67108864);                 // 2 MB (after CV dead)
    // Region D (96M..): small
    float* bv0  = (float*)(W + 100663296);
    int*   bi0  = (int*)  (W + 100663296 + 16384);
    float* bv1  = (float*)(W + 100663296 + 32768);
    int*   bi1  = (int*)  (W + 100663296 + 49152);
    float* ssum = (float*)(W + 100663296 + 65536);

    // 1. convert inputs for QKV GEMM
    sconv_kernel<<<4096, 256, 0, stream>>>(x, xh, xl);
    wtrans_kernel<<<dim3(48, 16), 256, 0, stream>>>(W_qkv, 1024, 3072, Wqh, Wql);
    // 2. QKV = x @ W_qkv + b  (split bf16, fp32-grade)
    gemm_nt_kernel<true><<<dim3(24, 32), 256, 0, stream>>>(xh, xl, 1024, Wqh, Wql, 1024,
                                                           b_qkv, QKV, 3072, 1024);
    // 3. q -> mh_rms -> Qb split [h][n][d]
    qconv_kernel<<<16384, 256, 0, stream>>>(QKV, gamma_q, Qbh, Qbl);
    // 4. normalized bf16 copies for sim (one launch)
    kbn3_kernel<<<dim3(4096, 3), 256, 0, stream>>>(QKV, k0, k1, kbn, k01bn);
    // 5. sim + top-1 over concatenated [k0;k1] (one launch)
    simmax_mfma<<<dim3(64, 32), 256, 0, stream>>>(kbn, k01bn, pval, pidx);
    simreduce2_kernel<<<16, 256, 0, stream>>>(pval, pidx, bv0, bi0, bv1, bi1);
    // 6. combine (+mh_rms k fused; sk cancels) -> CKh, CV fp32, sumsqs
    zero2_kernel<<<1, 64, 0, stream>>>(ssum);
    combine_kernel<<<4096, 256, 0, stream>>>(QKV, k0, v0, k1, v1, bv0, bi0, bv1, bi1,
                                             gamma_k, CKh, CV, ssum);
    // 7. V: scale by sv + transpose -> Vt bf16 [1024][4096]
    vt_kernel<<<dim3(64, 16), 256, 0, stream>>>(CV, ssum, Vt);
    // 8. W_out transpose -> bf16 (plain); CV dead after vt
    wtrans_kernel<<<dim3(16, 16), 256, 0, stream>>>(W_out, 1024, 1024, Wob, nullptr);
    // 9. flash attention (MFMA, split Q, plain K/P/V)
    attn_mfma<<<dim3(64, 16), 256, 0, stream>>>(Qbh, Qbl, CKh, Vt, Hb);
    // 10. out = Hb @ W_out^T + b_out (plain bf16)
    gemm_nt_kernel<false><<<dim3(8, 32), 256, 0, stream>>>(Hb, nullptr, 1024, Wob, nullptr, 1024,
                                                           b_out, out, 1024, 1024);
}